// Round 1
// baseline (60.086 us; speedup 1.0000x reference)
//
#include <hip/hip_runtime.h>
#include <hip/hip_bf16.h>

typedef __bf16 bf16x8 __attribute__((ext_vector_type(8)));
typedef float  f32x4  __attribute__((ext_vector_type(4)));

#define BATCH     262144
#define NTILES    (BATCH / 16)     // 16384 tiles of 16 rows
#define GEMM_BLOCKS 1024           // 4096 waves -> 4 tiles/wave

// ---------------------------------------------------------------------------
// Kernel 1: expand quaternion weight (32,32,4) -> W_eff (128x128) in bf16,
// laid out directly in MFMA B-fragment order:
//   wfrag[((nt*4 + kb)*64 + lane)*8 + j] = W_eff[nt*16 + (lane&15)][kb*32 + (lane>>4)*8 + j]
// so the GEMM kernel reads B-fragments as linear ds_read_b128.
// ---------------------------------------------------------------------------
__global__ __launch_bounds__(256) void prep_wfrag(const float* __restrict__ w,
                                                  ushort* __restrict__ wfrag) {
    int t = blockIdx.x * 256 + threadIdx.x;
    if (t >= 128 * 128) return;
    int j    = t & 7;
    int lane = (t >> 3) & 63;
    int kb   = (t >> 9) & 3;
    int nt   = t >> 11;
    int n = nt * 16 + (lane & 15);            // output feature 0..127
    int k = kb * 32 + (lane >> 4) * 8 + j;    // input feature 0..127
    int o  = n >> 2, c = n & 3;               // output quaternion, component
    int nq = k >> 2, d = k & 3;               // input quaternion, component
    // Hamilton product coefficient tables: out_c gets sign*w[comp] for x-component d
    const int   comp[4][4] = {{0,1,2,3},{1,0,3,2},{2,3,0,1},{3,2,1,0}};
    const float sgn [4][4] = {{ 1.f,-1.f,-1.f,-1.f},
                              { 1.f, 1.f, 1.f,-1.f},
                              { 1.f,-1.f, 1.f, 1.f},
                              { 1.f, 1.f,-1.f, 1.f}};
    float val = sgn[c][d] * w[o * 128 + nq * 4 + comp[c][d]];
    __bf16 bv = (__bf16)val;
    wfrag[t] = *reinterpret_cast<ushort*>(&bv);
}

// ---------------------------------------------------------------------------
// Kernel 2: out[262144x128] = x[262144x128] @ W_eff^T + bias, bf16 MFMA.
// Each wave independently owns 16-row tiles (grid-stride). W fragments live in
// LDS (32 KB), read as linear ds_read_b128 (conflict-free).
// ---------------------------------------------------------------------------
__global__ __launch_bounds__(256) void qgemm(const float* __restrict__ x,
                                             const ushort* __restrict__ wfrag,
                                             const float* __restrict__ bias,
                                             float* __restrict__ out) {
    __shared__ __align__(16) ushort wlds[16384];   // 32 KB: 8 nt x 4 kb x 64 lanes x 8 bf16

    int tid = threadIdx.x;
    // Cooperative linear 32 KB copy global -> LDS (8 x int4 per thread)
    {
        const int4* src = (const int4*)wfrag;
        int4*       dst = (int4*)wlds;
#pragma unroll
        for (int i = 0; i < 8; ++i) dst[tid + i * 256] = src[tid + i * 256];
    }

    int lane  = tid & 63;
    int wid   = tid >> 6;
    int row16 = lane & 15;     // A-row within tile == C-col within 16-tile
    int kgrp  = lane >> 4;     // 0..3

    // bias per n-tile: C/D col = lane&15
    float bv[8];
#pragma unroll
    for (int nt = 0; nt < 8; ++nt) bv[nt] = bias[nt * 16 + row16];

    __syncthreads();

    const bf16x8* blds = (const bf16x8*)wlds;
    int gwave = blockIdx.x * 4 + wid;   // 0..4095

    for (int tile = gwave; tile < NTILES; tile += GEMM_BLOCKS * 4) {
        const float* xt = x + (size_t)tile * 16 * 128;
        // A-fragment loads: lane reads 8 contiguous floats of row (lane&15)
        // at k = kb*32 + (lane>>4)*8, as 2x float4.
        const float4* xv = (const float4*)(xt + row16 * 128 + kgrp * 8);
        bf16x8 afr[4];
#pragma unroll
        for (int kb = 0; kb < 4; ++kb) {
            float4 p = xv[kb * 8 + 0];
            float4 q = xv[kb * 8 + 1];
            afr[kb][0] = (__bf16)p.x; afr[kb][1] = (__bf16)p.y;
            afr[kb][2] = (__bf16)p.z; afr[kb][3] = (__bf16)p.w;
            afr[kb][4] = (__bf16)q.x; afr[kb][5] = (__bf16)q.y;
            afr[kb][6] = (__bf16)q.z; afr[kb][7] = (__bf16)q.w;
        }

        // Compiler barrier: keep the (loop-invariant) LDS B-frag reads inside
        // the tile loop — hoisting them would burn 128 VGPRs and halve occupancy.
        asm volatile("" ::: "memory");

        // C/D layout (verified): col = lane&15, row = (lane>>4)*4 + reg
        float* op = out + (size_t)tile * 16 * 128 + (size_t)(kgrp * 4) * 128 + row16;
#pragma unroll
        for (int nt = 0; nt < 8; ++nt) {
            f32x4 acc = {bv[nt], bv[nt], bv[nt], bv[nt]};
#pragma unroll
            for (int kb = 0; kb < 4; ++kb) {
                bf16x8 bfr = blds[(nt * 4 + kb) * 64 + lane];
                acc = __builtin_amdgcn_mfma_f32_16x16x32_bf16(afr[kb], bfr, acc, 0, 0, 0);
            }
#pragma unroll
            for (int r = 0; r < 4; ++r) op[r * 128 + nt * 16] = acc[r];
        }
    }
}

extern "C" void kernel_launch(void* const* d_in, const int* in_sizes, int n_in,
                              void* d_out, int out_size, void* d_ws, size_t ws_size,
                              hipStream_t stream) {
    const float* x      = (const float*)d_in[0];   // [262144,128] fp32
    const float* weight = (const float*)d_in[1];   // [32,32,4] fp32
    const float* bias   = (const float*)d_in[2];   // [128] fp32
    float*       out    = (float*)d_out;           // [262144,128] fp32
    ushort*      wfrag  = (ushort*)d_ws;           // 32 KB fragment-ordered W_eff

    prep_wfrag<<<64, 256, 0, stream>>>(weight, wfrag);
    qgemm<<<GEMM_BLOCKS, 256, 0, stream>>>(x, wfrag, bias, out);
}

// Round 2
// 58.511 us; speedup vs baseline: 1.0269x; 1.0269x over previous
//
#include <hip/hip_runtime.h>
#include <hip/hip_bf16.h>

typedef __bf16 bf16x8 __attribute__((ext_vector_type(8)));
typedef float  f32x4  __attribute__((ext_vector_type(4)));

#define BATCH       262144
#define NTILES      (BATCH / 16)   // 16384 tiles of 16 rows
#define GEMM_BLOCKS 1024           // x 8 waves = 8192 waves -> 2 tiles/wave

// ---------------------------------------------------------------------------
// Kernel 1: expand quaternion weight (32,32,4) -> W_eff (128x128) in bf16,
// laid out in MFMA A-fragment order (W is now the A operand):
//   wfrag[((nt*4 + kb)*64 + lane)*8 + j] = W_eff[nt*16 + (lane&15)][kb*32 + (lane>>4)*8 + j]
// ---------------------------------------------------------------------------
__global__ __launch_bounds__(256) void prep_wfrag(const float* __restrict__ w,
                                                  ushort* __restrict__ wfrag) {
    int t = blockIdx.x * 256 + threadIdx.x;
    if (t >= 128 * 128) return;
    int j    = t & 7;
    int lane = (t >> 3) & 63;
    int kb   = (t >> 9) & 3;
    int nt   = t >> 11;
    int n = nt * 16 + (lane & 15);            // output feature 0..127
    int k = kb * 32 + (lane >> 4) * 8 + j;    // input feature 0..127
    int o  = n >> 2, c = n & 3;               // output quaternion, component
    int nq = k >> 2, d = k & 3;               // input quaternion, component
    const int   comp[4][4] = {{0,1,2,3},{1,0,3,2},{2,3,0,1},{3,2,1,0}};
    const float sgn [4][4] = {{ 1.f,-1.f,-1.f,-1.f},
                              { 1.f, 1.f, 1.f,-1.f},
                              { 1.f,-1.f, 1.f, 1.f},
                              { 1.f, 1.f,-1.f, 1.f}};
    float val = sgn[c][d] * w[o * 128 + nq * 4 + comp[c][d]];
    __bf16 bv = (__bf16)val;
    wfrag[t] = *reinterpret_cast<ushort*>(&bv);
}

// ---------------------------------------------------------------------------
// Kernel 2: out = x @ W_eff^T + bias.  W is the MFMA A-operand, x is B, so
// D's rows are features -> each lane holds 4 consecutive features of one
// batch row -> float4 non-temporal stores.
// ---------------------------------------------------------------------------
__global__ __launch_bounds__(512, 8) void qgemm(const float* __restrict__ x,
                                                const ushort* __restrict__ wfrag,
                                                const float* __restrict__ bias,
                                                float* __restrict__ out) {
    __shared__ __align__(16) ushort wlds[16384];   // 32 KB B-fragment-ordered W
    __shared__ __align__(16) float  sbias[128];

    int tid = threadIdx.x;
    // Cooperative linear 32 KB copy global -> LDS (4 x int4 per thread)
    {
        const int4* src = (const int4*)wfrag;
        int4*       dst = (int4*)wlds;
#pragma unroll
        for (int i = 0; i < 4; ++i) dst[tid + i * 512] = src[tid + i * 512];
    }
    if (tid < 128) sbias[tid] = bias[tid];

    int lane  = tid & 63;
    int wid   = tid >> 6;      // 0..7
    int row16 = lane & 15;     // batch row within tile == D col
    int kgrp  = lane >> 4;     // 0..3

    __syncthreads();

    const bf16x8* blds = (const bf16x8*)wlds;
    int gwave = blockIdx.x * 8 + wid;   // 0..8191

    for (int tile = gwave; tile < NTILES; tile += GEMM_BLOCKS * 8) {
        const float* xt = x + (size_t)tile * 16 * 128;
        // x fragment (B operand): lane holds x[row16][kb*32 + kgrp*8 .. +7]
        const float4* xv = (const float4*)(xt + row16 * 128 + kgrp * 8);
        bf16x8 afr[4];
#pragma unroll
        for (int kb = 0; kb < 4; ++kb) {
            float4 p = xv[kb * 8 + 0];
            float4 q = xv[kb * 8 + 1];
            afr[kb][0] = (__bf16)p.x; afr[kb][1] = (__bf16)p.y;
            afr[kb][2] = (__bf16)p.z; afr[kb][3] = (__bf16)p.w;
            afr[kb][4] = (__bf16)q.x; afr[kb][5] = (__bf16)q.y;
            afr[kb][6] = (__bf16)q.z; afr[kb][7] = (__bf16)q.w;
        }

        // Compiler barrier: keep loop-invariant LDS reads inside the loop
        // (hoisting 32 B-frags would burn 128 VGPRs and kill occupancy).
        asm volatile("" ::: "memory");

        // D layout: col = lane&15 = batch row, row = kgrp*4 + r = feature.
        // Lane stores features nt*16 + kgrp*4 .. +3 of batch row row16.
        float* op = out + (size_t)tile * 16 * 128 + row16 * 128 + kgrp * 4;
#pragma unroll
        for (int nt = 0; nt < 8; ++nt) {
            f32x4 acc = *(const f32x4*)&sbias[nt * 16 + kgrp * 4];
#pragma unroll
            for (int kb = 0; kb < 4; ++kb) {
                bf16x8 wfr = blds[(nt * 4 + kb) * 64 + lane];
                acc = __builtin_amdgcn_mfma_f32_16x16x32_bf16(wfr, afr[kb], acc, 0, 0, 0);
            }
            __builtin_nontemporal_store(*(f32x4*)&acc, (f32x4*)(op + nt * 16));
        }
    }
}

extern "C" void kernel_launch(void* const* d_in, const int* in_sizes, int n_in,
                              void* d_out, int out_size, void* d_ws, size_t ws_size,
                              hipStream_t stream) {
    const float* x      = (const float*)d_in[0];   // [262144,128] fp32
    const float* weight = (const float*)d_in[1];   // [32,32,4] fp32
    const float* bias   = (const float*)d_in[2];   // [128] fp32
    float*       out    = (float*)d_out;           // [262144,128] fp32
    ushort*      wfrag  = (ushort*)d_ws;           // 32 KB fragment-ordered W_eff

    prep_wfrag<<<64, 256, 0, stream>>>(weight, wfrag);
    qgemm<<<GEMM_BLOCKS, 512, 0, stream>>>(x, wfrag, bias, out);
}

// Round 3
// 56.602 us; speedup vs baseline: 1.0616x; 1.0337x over previous
//
#include <hip/hip_runtime.h>
#include <hip/hip_bf16.h>

typedef __bf16 bf16x8 __attribute__((ext_vector_type(8)));
typedef float  f32x4  __attribute__((ext_vector_type(4)));

#define BATCH       262144
#define NTILES      (BATCH / 16)   // 16384 tiles of 16 rows
#define GEMM_BLOCKS 1024           // x 8 waves = 8192 waves -> 2 tiles/wave

// ---------------------------------------------------------------------------
// Single fused kernel: out[262144x128] = x @ W_eff^T + bias.
//
// W_eff (128x128 sign-permuted expansion of the (32,32,4) quaternion weight)
// is built IN-BLOCK into LDS, directly in MFMA A-fragment order, with the
// k-axis PERMUTED so that the x (B-operand) loads are full-granule coalesced:
//   fragment position (kgrp=lane>>4, j) holds physical
//     k = kb*32 + (j<4 ? kgrp*4+j : 16 + kgrp*4 + (j-4))
// so lane's two float4 x-loads sit at byte offsets row*512 + kb*128 + kgrp*16
// (+64): every load instruction covers 32 FULLY-USED 64B granules.
// The same permutation is applied to both MFMA operands -> sum over k is
// unchanged -> bitwise-identical math.
// ---------------------------------------------------------------------------
__global__ __launch_bounds__(512, 8) void qgemm(const float* __restrict__ x,
                                                const float* __restrict__ w,
                                                const float* __restrict__ bias,
                                                float* __restrict__ out) {
    __shared__ __align__(16) ushort wlds[16384];   // 32 KB: 8 nt x 4 kb x 64 lanes x 8 bf16
    __shared__ __align__(16) float  sbias[128];

    int tid = threadIdx.x;

    // ---- Build W_eff fragments in LDS (2048 fragments, 4 per thread) ----
#pragma unroll
    for (int i = 0; i < 4; ++i) {
        int f    = tid + i * 512;      // fragment index = (nt*4 + kb)*64 + lane
        int lane = f & 63;
        int kb   = (f >> 6) & 3;
        int nt   = f >> 8;
        int g    = lane >> 4;
        int n    = nt * 16 + (lane & 15);   // output feature 0..127
        int o = n >> 2, c = n & 3;          // output quaternion, component
        bf16x8 bv;
#pragma unroll
        for (int j = 0; j < 8; ++j) {
            int k  = kb * 32 + (j < 4 ? g * 4 + j : 16 + g * 4 + (j - 4));
            int nq = k >> 2, d = k & 3;     // input quaternion, component
            // Hamilton table via bit-math (no runtime-indexed arrays -> no scratch):
            //   component index = c ^ d;  sign: +1 on diagonal/cyclic, else -1
            int comp = c ^ d;
            bool neg = (d != 0) && ((c == 0) || (c != d && d != (c % 3) + 1));
            float val = w[o * 128 + nq * 4 + comp];
            val = neg ? -val : val;
            bv[j] = (__bf16)val;
        }
        *reinterpret_cast<bf16x8*>(&wlds[f * 8]) = bv;
    }
    if (tid < 128) sbias[tid] = bias[tid];

    int lane  = tid & 63;
    int wid   = tid >> 6;      // 0..7
    int row16 = lane & 15;     // batch row within tile == D col
    int kgrp  = lane >> 4;     // 0..3

    __syncthreads();

    const bf16x8* blds = (const bf16x8*)wlds;
    int gwave = blockIdx.x * 8 + wid;   // 0..8191

    for (int tile = gwave; tile < NTILES; tile += GEMM_BLOCKS * 8) {
        // x fragment (B operand), k-permuted: lane reads float4 at
        // [row16][kb*32 + kgrp*4] and [row16][kb*32 + 16 + kgrp*4].
        const float4* xv = (const float4*)(x + (size_t)tile * 16 * 128 + row16 * 128);
        bf16x8 afr[4];
#pragma unroll
        for (int kb = 0; kb < 4; ++kb) {
            float4 p = xv[kb * 8 + kgrp];
            float4 q = xv[kb * 8 + kgrp + 4];
            afr[kb][0] = (__bf16)p.x; afr[kb][1] = (__bf16)p.y;
            afr[kb][2] = (__bf16)p.z; afr[kb][3] = (__bf16)p.w;
            afr[kb][4] = (__bf16)q.x; afr[kb][5] = (__bf16)q.y;
            afr[kb][6] = (__bf16)q.z; afr[kb][7] = (__bf16)q.w;
        }

        // Compiler barrier: keep loop-invariant LDS reads inside the loop
        // (hoisting 32 B-frags would burn 128 VGPRs and kill occupancy).
        asm volatile("" ::: "memory");

        // D layout: col = lane&15 = batch row, row = kgrp*4 + r = feature.
        // Lane stores features nt*16 + kgrp*4 .. +3 of its batch row (float4,
        // 4 lanes cover each 64B granule fully).
        float* op = out + (size_t)tile * 16 * 128 + row16 * 128 + kgrp * 4;
#pragma unroll
        for (int nt = 0; nt < 8; ++nt) {
            f32x4 acc = *(const f32x4*)&sbias[nt * 16 + kgrp * 4];
#pragma unroll
            for (int kb = 0; kb < 4; ++kb) {
                bf16x8 wfr = blds[(nt * 4 + kb) * 64 + lane];
                acc = __builtin_amdgcn_mfma_f32_16x16x32_bf16(wfr, afr[kb], acc, 0, 0, 0);
            }
            *(f32x4*)(op + nt * 16) = acc;
        }
    }
}

extern "C" void kernel_launch(void* const* d_in, const int* in_sizes, int n_in,
                              void* d_out, int out_size, void* d_ws, size_t ws_size,
                              hipStream_t stream) {
    const float* x      = (const float*)d_in[0];   // [262144,128] fp32
    const float* weight = (const float*)d_in[1];   // [32,32,4] fp32
    const float* bias   = (const float*)d_in[2];   // [128] fp32
    float*       out    = (float*)d_out;           // [262144,128] fp32

    qgemm<<<GEMM_BLOCKS, 512, 0, stream>>>(x, weight, bias, out);
}

// Round 4
// 54.137 us; speedup vs baseline: 1.1099x; 1.0455x over previous
//
#include <hip/hip_runtime.h>
#include <hip/hip_bf16.h>

typedef __bf16 bf16x8 __attribute__((ext_vector_type(8)));
typedef float  f32x4  __attribute__((ext_vector_type(4)));

#define BATCH       262144
#define NTILES      (BATCH / 16)   // 16384 tiles of 16 rows
#define GEMM_BLOCKS 1024           // x 8 waves = 8192 waves -> exactly 2 tiles/wave

// ---------------------------------------------------------------------------
// Kernel 1 (one-shot, 64 blocks): expand quaternion weight (32,32,4) ->
// W_eff (128x128) in bf16, in MFMA A-fragment order with the k-axis PERMUTED
// so the main kernel's x loads are full-granule coalesced:
//   element j of fragment (nt,kb,lane) holds physical
//     k = kb*32 + (j<4 ? g*4+j : 16 + g*4 + (j-4)),  g = lane>>4
// The same permutation is applied to both MFMA operands -> identical math.
// ---------------------------------------------------------------------------
__global__ __launch_bounds__(256) void prep_wfrag(const float* __restrict__ w,
                                                  ushort* __restrict__ wfrag) {
    int t = blockIdx.x * 256 + threadIdx.x;   // fragment-element index
    if (t >= 128 * 128) return;
    int j    = t & 7;
    int lane = (t >> 3) & 63;
    int kb   = (t >> 9) & 3;
    int nt   = t >> 11;
    int g    = lane >> 4;
    int n = nt * 16 + (lane & 15);                          // output feature
    int k = kb * 32 + (j < 4 ? g * 4 + j : 16 + g * 4 + (j - 4));  // input feature
    int o  = n >> 2, c = n & 3;
    int nq = k >> 2, d = k & 3;
    // Hamilton product, bit-math form (verified on HW, rounds 1-3):
    int comp = c ^ d;
    bool neg = (d != 0) && ((c == 0) || (c != d && d != (c % 3) + 1));
    float val = w[o * 128 + nq * 4 + comp];
    val = neg ? -val : val;
    __bf16 bv = (__bf16)val;
    wfrag[t] = *reinterpret_cast<ushort*>(&bv);
}

// ---------------------------------------------------------------------------
// Kernel 2: out = x @ W_eff^T + bias.  Each wave owns exactly 2 tiles
// (tile gwave and gwave+8192), with BOTH tiles' x loads issued up front so
// tile-1's HBM latency hides under tile-0's compute.
// ---------------------------------------------------------------------------
__global__ __launch_bounds__(512, 4) void qgemm(const float* __restrict__ x,
                                                const ushort* __restrict__ wfrag,
                                                const float* __restrict__ bias,
                                                float* __restrict__ out) {
    __shared__ __align__(16) ushort wlds[16384];   // 32 KB fragment-ordered W
    __shared__ __align__(16) float  sbias[128];

    int tid = threadIdx.x;
    {   // cheap setup: linear 32 KB copy (L2-hot after first block)
        const int4* src = (const int4*)wfrag;
        int4*       dst = (int4*)wlds;
#pragma unroll
        for (int i = 0; i < 4; ++i) dst[tid + i * 512] = src[tid + i * 512];
    }
    if (tid < 128) sbias[tid] = bias[tid];

    int lane  = tid & 63;
    int wid   = tid >> 6;
    int row16 = lane & 15;     // batch row within tile == D col
    int kgrp  = lane >> 4;     // 0..3

    __syncthreads();

    const bf16x8* blds = (const bf16x8*)wlds;
    int gwave = blockIdx.x * 8 + wid;            // 0..8191
    size_t t0 = (size_t)gwave;
    size_t t1 = (size_t)gwave + 8192;

    // ---- issue ALL global loads for both tiles (16 x dwordx4 in flight) ----
    const float4* xv0 = (const float4*)(x + t0 * 2048 + row16 * 128);
    const float4* xv1 = (const float4*)(x + t1 * 2048 + row16 * 128);
    float4 r0[8], r1[8];
#pragma unroll
    for (int kb = 0; kb < 4; ++kb) {
        r0[2 * kb]     = xv0[kb * 8 + kgrp];
        r0[2 * kb + 1] = xv0[kb * 8 + kgrp + 4];
    }
#pragma unroll
    for (int kb = 0; kb < 4; ++kb) {
        r1[2 * kb]     = xv1[kb * 8 + kgrp];
        r1[2 * kb + 1] = xv1[kb * 8 + kgrp + 4];
    }

    auto run_tile = [&](const float4* r, size_t tile) {
        bf16x8 afr[4];
#pragma unroll
        for (int kb = 0; kb < 4; ++kb) {
            float4 p = r[2 * kb], q = r[2 * kb + 1];
            afr[kb][0] = (__bf16)p.x; afr[kb][1] = (__bf16)p.y;
            afr[kb][2] = (__bf16)p.z; afr[kb][3] = (__bf16)p.w;
            afr[kb][4] = (__bf16)q.x; afr[kb][5] = (__bf16)q.y;
            afr[kb][6] = (__bf16)q.z; afr[kb][7] = (__bf16)q.w;
        }
        // D layout: col = lane&15 = batch row, row = kgrp*4 + r = feature.
        float* op = out + tile * 2048 + row16 * 128 + kgrp * 4;
#pragma unroll
        for (int nt = 0; nt < 8; ++nt) {
            f32x4 acc = *(const f32x4*)&sbias[nt * 16 + kgrp * 4];
#pragma unroll
            for (int kb = 0; kb < 4; ++kb) {
                bf16x8 wfr = blds[(nt * 4 + kb) * 64 + lane];
                acc = __builtin_amdgcn_mfma_f32_16x16x32_bf16(wfr, afr[kb], acc, 0, 0, 0);
            }
            *(f32x4*)(op + nt * 16) = acc;
        }
    };

    run_tile(r0, t0);
    // Clobber between tiles only: stops W-frag CSE (register blow-up) but the
    // r1 global loads are already issued above it.
    asm volatile("" ::: "memory");
    run_tile(r1, t1);
}

extern "C" void kernel_launch(void* const* d_in, const int* in_sizes, int n_in,
                              void* d_out, int out_size, void* d_ws, size_t ws_size,
                              hipStream_t stream) {
    const float* x      = (const float*)d_in[0];   // [262144,128] fp32
    const float* weight = (const float*)d_in[1];   // [32,32,4] fp32
    const float* bias   = (const float*)d_in[2];   // [128] fp32
    float*       out    = (float*)d_out;           // [262144,128] fp32
    ushort*      wfrag  = (ushort*)d_ws;           // 32 KB fragment-ordered W_eff

    prep_wfrag<<<64, 256, 0, stream>>>(weight, wfrag);
    qgemm<<<GEMM_BLOCKS, 512, 0, stream>>>(x, wfrag, bias, out);
}